// Round 1
// baseline (592.558 us; speedup 1.0000x reference)
//
#include <hip/hip_runtime.h>

#define T_TOKENS 8192
#define IN_F 4096
#define OUT_F 11008

#define BM 128
#define BN 128
#define BK 128

typedef __attribute__((ext_vector_type(4))) int v4i;
typedef __attribute__((ext_vector_type(16))) int v16i;

__device__ __forceinline__ void load_lds16(const void* g, void* l) {
    __builtin_amdgcn_global_load_lds(
        (const __attribute__((address_space(1))) void*)g,
        (__attribute__((address_space(3))) void*)l, 16, 0, 0);
}

// ---------------- Pass 1: per-token activation quantization ----------------
// One block per token row (4096 f32). 256 threads * 16 floats each.
__global__ __launch_bounds__(256) void quant_kernel(
        const float* __restrict__ x, signed char* __restrict__ xq,
        float* __restrict__ qscale) {
    const int row = blockIdx.x;
    const float4* xr = (const float4*)(x + (size_t)row * IN_F);
    float4 v[4];
    float am = 0.f;
#pragma unroll
    for (int i = 0; i < 4; ++i) {
        v[i] = xr[threadIdx.x + i * 256];
        am = fmaxf(am, fmaxf(fmaxf(fabsf(v[i].x), fabsf(v[i].y)),
                             fmaxf(fabsf(v[i].z), fabsf(v[i].w))));
    }
#pragma unroll
    for (int off = 32; off > 0; off >>= 1)
        am = fmaxf(am, __shfl_xor(am, off, 64));
    __shared__ float wmax[4];
    const int wid = threadIdx.x >> 6;
    if ((threadIdx.x & 63) == 0) wmax[wid] = am;
    __syncthreads();
    float amax = fmaxf(fmaxf(wmax[0], wmax[1]), fmaxf(wmax[2], wmax[3]));
    float qs = amax * (1.0f / 127.0f);
    if (qs < 1e-30f) qs = 1e-30f;
    const float inv = 1.0f / qs;
    if (threadIdx.x == 0) qscale[row] = qs;
    int* xqo = (int*)(xq + (size_t)row * IN_F);
#pragma unroll
    for (int i = 0; i < 4; ++i) {
        int q0 = (int)rintf(v[i].x * inv);
        int q1 = (int)rintf(v[i].y * inv);
        int q2 = (int)rintf(v[i].z * inv);
        int q3 = (int)rintf(v[i].w * inv);
        q0 = max(-128, min(127, q0));
        q1 = max(-128, min(127, q1));
        q2 = max(-128, min(127, q2));
        q3 = max(-128, min(127, q3));
        unsigned p = (unsigned)(q0 & 255) | ((unsigned)(q1 & 255) << 8) |
                     ((unsigned)(q2 & 255) << 16) | ((unsigned)(q3 & 255) << 24);
        xqo[threadIdx.x + i * 256] = (int)p;
    }
}

// ---------------- Pass 2: weight int32 -> int8 repack ----------------
__global__ __launch_bounds__(256) void repack_kernel(
        const int* __restrict__ w32, signed char* __restrict__ w8, int n4) {
    int idx = blockIdx.x * 256 + threadIdx.x;
    const int stride = gridDim.x * 256;
    for (int i = idx; i < n4; i += stride) {
        v4i w = ((const v4i*)w32)[i];
        unsigned p = (unsigned)(w[0] & 255) | ((unsigned)(w[1] & 255) << 8) |
                     ((unsigned)(w[2] & 255) << 16) | ((unsigned)(w[3] & 255) << 24);
        ((int*)w8)[i] = (int)p;
    }
}

// ---------------- Pass 3: int8 GEMM, 128x128 tile, BK=128 ----------------
// A = xq [8192][4096] (row-major, K contiguous), B = w8 [11008][4096] (B^T form).
// 4 waves in 2x2; each wave owns 64x64 via 2x2 fragments of mfma_i32_32x32x32_i8.
// LDS XOR-swizzle (row&7)<<4, applied on pre-swizzled GLOBAL source for
// global_load_lds (linear LDS dest) and on the ds_read address (same involution).
__global__ __launch_bounds__(256) void gemm_kernel(
        const signed char* __restrict__ A, const signed char* __restrict__ B,
        const float* __restrict__ qscale, const float* __restrict__ bias,
        const float* __restrict__ dqs, float* __restrict__ out) {
    __shared__ __align__(16) signed char As[BM * BK];
    __shared__ __align__(16) signed char Bs[BN * BK];

    const int tid = threadIdx.x;
    const int wid = tid >> 6;
    const int lane = tid & 63;
    const int wm = wid >> 1;   // 0..1
    const int wn = wid & 1;    // 0..1
    const int l31 = lane & 31;
    const int hi = lane >> 5;  // 0..1

    const int m0 = blockIdx.x * BM;
    const int n0 = blockIdx.y * BN;
    const signed char* Ap = A + (size_t)m0 * IN_F;
    const signed char* Bp = B + (size_t)n0 * IN_F;

    v16i acc[2][2] = {};

    for (int kk = 0; kk < IN_F; kk += BK) {
        // ---- stage A and B tiles (16 KB each) via global_load_lds w=16 ----
#pragma unroll
        for (int c = 0; c < 4; ++c) {
            int L = c * 4096 + tid * 16;         // full linear LDS offset
            int row = L >> 7;                    // 0..127
            int slot = (L >> 4) & 7;
            int col = ((slot ^ (row & 7)) << 4); // pre-swizzled source column
            load_lds16(Ap + (size_t)row * IN_F + kk + col,
                       As + c * 4096 + wid * 1024);
        }
#pragma unroll
        for (int c = 0; c < 4; ++c) {
            int L = c * 4096 + tid * 16;
            int row = L >> 7;
            int slot = (L >> 4) & 7;
            int col = ((slot ^ (row & 7)) << 4);
            load_lds16(Bp + (size_t)row * IN_F + kk + col,
                       Bs + c * 4096 + wid * 1024);
        }
        __syncthreads();  // drains vmcnt + lgkmcnt

        // ---- compute: 4 k-steps of 32 ----
#pragma unroll
        for (int ks = 0; ks < 4; ++ks) {
            v4i a[2], b[2];
            const int c16 = ks * 2 + hi;
#pragma unroll
            for (int im = 0; im < 2; ++im) {
                int row = wm * 64 + im * 32 + l31;
                a[im] = *(const v4i*)(As + row * BK + ((c16 ^ (row & 7)) << 4));
            }
#pragma unroll
            for (int in = 0; in < 2; ++in) {
                int row = wn * 64 + in * 32 + l31;
                b[in] = *(const v4i*)(Bs + row * BK + ((c16 ^ (row & 7)) << 4));
            }
#pragma unroll
            for (int im = 0; im < 2; ++im)
#pragma unroll
                for (int in = 0; in < 2; ++in)
                    acc[im][in] = __builtin_amdgcn_mfma_i32_32x32x32_i8(
                        a[im], b[in], acc[im][in], 0, 0, 0);
        }
        __syncthreads();  // protect LDS before next stage
    }

    // ---- epilogue: dequant + bias ----
    const float dq = dqs[0];
#pragma unroll
    for (int im = 0; im < 2; ++im) {
        float qsv[16];
#pragma unroll
        for (int r = 0; r < 16; ++r) {
            int trow = wm * 64 + im * 32 + (r & 3) + 8 * (r >> 2) + 4 * hi;
            qsv[r] = dq * qscale[m0 + trow];
        }
#pragma unroll
        for (int in = 0; in < 2; ++in) {
            const int col = n0 + wn * 64 + in * 32 + l31;
            const float bv = bias[col];
#pragma unroll
            for (int r = 0; r < 16; ++r) {
                int trow = wm * 64 + im * 32 + (r & 3) + 8 * (r >> 2) + 4 * hi;
                out[(size_t)(m0 + trow) * OUT_F + col] =
                    qsv[r] * (float)acc[im][in][r] + bv;
            }
        }
    }
}

extern "C" void kernel_launch(void* const* d_in, const int* in_sizes, int n_in,
                              void* d_out, int out_size, void* d_ws, size_t ws_size,
                              hipStream_t stream) {
    const float* x    = (const float*)d_in[0];
    const int*   w32  = (const int*)d_in[1];   // int8 values stored as int32
    const float* bias = (const float*)d_in[2];
    const float* dqs  = (const float*)d_in[3];
    float* out = (float*)d_out;

    signed char* xq = (signed char*)d_ws;                                   // 33.55 MB
    float* qscale   = (float*)((char*)d_ws + (size_t)T_TOKENS * IN_F);      // 32 KB
    signed char* w8 = (signed char*)((char*)d_ws + (size_t)T_TOKENS * IN_F
                                     + (size_t)T_TOKENS * 4);               // 45 MB

    quant_kernel<<<T_TOKENS, 256, 0, stream>>>(x, xq, qscale);
    repack_kernel<<<2048, 256, 0, stream>>>(w32, w8, OUT_F * IN_F / 4);
    dim3 g(T_TOKENS / BM, OUT_F / BN);
    gemm_kernel<<<g, 256, 0, stream>>>(xq, w8, qscale, bias, dqs, out);
}

// Round 2
// 557.603 us; speedup vs baseline: 1.0627x; 1.0627x over previous
//
#include <hip/hip_runtime.h>

#define T_TOKENS 8192
#define IN_F 4096
#define OUT_F 11008

#define BM 256
#define BN 256
#define BK 64
#define NT (IN_F / BK)  // 64 K-tiles

typedef __attribute__((ext_vector_type(4))) int v4i;
typedef __attribute__((ext_vector_type(16))) int v16i;

__device__ __forceinline__ void load_lds16(const signed char* g, const signed char* l) {
    __builtin_amdgcn_global_load_lds(
        (const __attribute__((address_space(1))) void*)g,
        (__attribute__((address_space(3))) void*)l, 16, 0, 0);
}

// ---------------- Pass 1: per-token activation quantization ----------------
__global__ __launch_bounds__(256) void quant_kernel(
        const float* __restrict__ x, signed char* __restrict__ xq,
        float* __restrict__ qscale) {
    const int row = blockIdx.x;
    const float4* xr = (const float4*)(x + (size_t)row * IN_F);
    float4 v[4];
    float am = 0.f;
#pragma unroll
    for (int i = 0; i < 4; ++i) {
        v[i] = xr[threadIdx.x + i * 256];
        am = fmaxf(am, fmaxf(fmaxf(fabsf(v[i].x), fabsf(v[i].y)),
                             fmaxf(fabsf(v[i].z), fabsf(v[i].w))));
    }
#pragma unroll
    for (int off = 32; off > 0; off >>= 1)
        am = fmaxf(am, __shfl_xor(am, off, 64));
    __shared__ float wmax[4];
    const int wid = threadIdx.x >> 6;
    if ((threadIdx.x & 63) == 0) wmax[wid] = am;
    __syncthreads();
    float amax = fmaxf(fmaxf(wmax[0], wmax[1]), fmaxf(wmax[2], wmax[3]));
    float qs = amax * (1.0f / 127.0f);
    if (qs < 1e-30f) qs = 1e-30f;
    const float inv = 1.0f / qs;
    if (threadIdx.x == 0) qscale[row] = qs;
    int* xqo = (int*)(xq + (size_t)row * IN_F);
#pragma unroll
    for (int i = 0; i < 4; ++i) {
        int q0 = (int)rintf(v[i].x * inv);
        int q1 = (int)rintf(v[i].y * inv);
        int q2 = (int)rintf(v[i].z * inv);
        int q3 = (int)rintf(v[i].w * inv);
        q0 = max(-128, min(127, q0));
        q1 = max(-128, min(127, q1));
        q2 = max(-128, min(127, q2));
        q3 = max(-128, min(127, q3));
        unsigned p = (unsigned)(q0 & 255) | ((unsigned)(q1 & 255) << 8) |
                     ((unsigned)(q2 & 255) << 16) | ((unsigned)(q3 & 255) << 24);
        xqo[threadIdx.x + i * 256] = (int)p;
    }
}

// ---------------- Pass 2: weight int32 -> int8 repack ----------------
__global__ __launch_bounds__(256) void repack_kernel(
        const int* __restrict__ w32, signed char* __restrict__ w8, int n4) {
    int idx = blockIdx.x * 256 + threadIdx.x;
    const int stride = gridDim.x * 256;
    for (int i = idx; i < n4; i += stride) {
        v4i w = ((const v4i*)w32)[i];
        unsigned p = (unsigned)(w[0] & 255) | ((unsigned)(w[1] & 255) << 8) |
                     ((unsigned)(w[2] & 255) << 16) | ((unsigned)(w[3] & 255) << 24);
        ((int*)w8)[i] = (int)p;
    }
}

// ---------------- Pass 3: int8 GEMM, 256x256 tile, BK=64, depth-2 pipeline ----
// A = xq [8192][4096], B = w8 [11008][4096] (B^T form). 8 waves (2M x 4N),
// per-wave 128x64 output via acc[4][2] of mfma_i32_32x32x32_i8.
// LDS: 3 buffers x (A 16KB + B 16KB). Swizzle: slot' = slot ^ ((row>>1)&3)
// (16B slots in 64B rows) -> 8 consecutive rows cover all 32 banks.
// Applied on pre-swizzled GLOBAL source (gload_lds dest stays linear) and on
// the ds_read address (same involution).
__global__ __launch_bounds__(512, 2) void gemm_kernel(
        const signed char* __restrict__ A, const signed char* __restrict__ B,
        const float* __restrict__ qscale, const float* __restrict__ bias,
        const float* __restrict__ dqs, float* __restrict__ out) {
    __shared__ __align__(16) signed char smem[3 * 32768];  // [buf][A 16K | B 16K]

    const int tid = threadIdx.x;
    const int wid = tid >> 6;   // 0..7
    const int lane = tid & 63;
    const int wm = wid >> 2;    // 0..1
    const int wn = wid & 3;     // 0..3
    const int l31 = lane & 31;
    const int hi = lane >> 5;

    // T1: XCD-aware bijective swizzle (1376 blocks = 8 * 172)
    const int wg = ((int)blockIdx.x & 7) * 172 + ((int)blockIdx.x >> 3);
    const int m0 = (wg & 31) * BM;   // 32 m-tiles (column-major: m fastest)
    const int n0 = (wg >> 5) * BN;   // 43 n-tiles

    // ---- staging source/dest precompute (2 A-chunks + 2 B-chunks / thread) ----
    const signed char* aSrc[2];
    const signed char* bSrc[2];
    int ldsDst[2];
#pragma unroll
    for (int c = 0; c < 2; ++c) {
        const int L = c * 8192 + tid * 16;          // linear LDS byte offset
        const int row = L >> 6;                     // 0..255
        const int slot = (L >> 4) & 3;
        const int col = ((slot ^ ((row >> 1) & 3)) << 4);  // pre-swizzled source
        aSrc[c] = A + (size_t)(m0 + row) * IN_F + col;
        bSrc[c] = B + (size_t)(n0 + row) * IN_F + col;
        ldsDst[c] = c * 8192 + wid * 1024;          // wave-uniform (+lane*16 by HW)
    }
    auto STAGE = [&](int bufBase, int koff) {
#pragma unroll
        for (int c = 0; c < 2; ++c)
            load_lds16(aSrc[c] + koff, smem + bufBase + ldsDst[c]);
#pragma unroll
        for (int c = 0; c < 2; ++c)
            load_lds16(bSrc[c] + koff, smem + bufBase + 16384 + ldsDst[c]);
    };

    // ---- fragment LDS offsets (within buffer), swizzled ----
    int aOff[4][2], bOff[2][2];
#pragma unroll
    for (int im = 0; im < 4; ++im) {
        const int r = wm * 128 + im * 32 + l31;
#pragma unroll
        for (int ks = 0; ks < 2; ++ks) {
            const int c16 = ks * 2 + hi;
            aOff[im][ks] = r * 64 + ((c16 ^ ((r >> 1) & 3)) << 4);
        }
    }
#pragma unroll
    for (int in = 0; in < 2; ++in) {
        const int r = wn * 64 + in * 32 + l31;
#pragma unroll
        for (int ks = 0; ks < 2; ++ks) {
            const int c16 = ks * 2 + hi;
            bOff[in][ks] = 16384 + r * 64 + ((c16 ^ ((r >> 1) & 3)) << 4);
        }
    }

    v16i acc[4][2] = {};

    int bb0 = 0, bb1 = 32768, bb2 = 65536;
    STAGE(bb0, 0);
    STAGE(bb1, BK);

    for (int t = 0; t < NT; ++t) {
        // T4: counted vmcnt — only tile t+1's 4 loads may remain in flight.
        if (t + 1 < NT) {
            asm volatile("s_waitcnt vmcnt(4)" ::: "memory");
        } else {
            asm volatile("s_waitcnt vmcnt(0)" ::: "memory");
        }
        __builtin_amdgcn_sched_barrier(0);
        __builtin_amdgcn_s_barrier();   // all waves: tile t visible, t-1 reads done
        __builtin_amdgcn_sched_barrier(0);

        if (t + 2 < NT) STAGE(bb2, (t + 2) * BK);  // into tile (t-1)'s buffer

#pragma unroll
        for (int ks = 0; ks < 2; ++ks) {
            v4i a[4], b[2];
#pragma unroll
            for (int im = 0; im < 4; ++im)
                a[im] = *(const v4i*)(smem + bb0 + aOff[im][ks]);
#pragma unroll
            for (int in = 0; in < 2; ++in)
                b[in] = *(const v4i*)(smem + bb0 + bOff[in][ks]);
            __builtin_amdgcn_s_setprio(1);  // T5
#pragma unroll
            for (int im = 0; im < 4; ++im)
#pragma unroll
                for (int in = 0; in < 2; ++in)
                    acc[im][in] = __builtin_amdgcn_mfma_i32_32x32x32_i8(
                        a[im], b[in], acc[im][in], 0, 0, 0);
            __builtin_amdgcn_s_setprio(0);
        }
        const int tmp = bb0; bb0 = bb1; bb1 = bb2; bb2 = tmp;
    }

    // ---- epilogue: dequant + bias ----
    const float dq = dqs[0];
#pragma unroll
    for (int im = 0; im < 4; ++im) {
        float qsv[16];
#pragma unroll
        for (int r = 0; r < 16; ++r) {
            const int trow = wm * 128 + im * 32 + (r & 3) + 8 * (r >> 2) + 4 * hi;
            qsv[r] = dq * qscale[m0 + trow];
        }
#pragma unroll
        for (int in = 0; in < 2; ++in) {
            const int col = n0 + wn * 64 + in * 32 + l31;
            const float bv = bias[col];
#pragma unroll
            for (int r = 0; r < 16; ++r) {
                const int trow = wm * 128 + im * 32 + (r & 3) + 8 * (r >> 2) + 4 * hi;
                out[(size_t)(m0 + trow) * OUT_F + col] =
                    qsv[r] * (float)acc[im][in][r] + bv;
            }
        }
    }
}

extern "C" void kernel_launch(void* const* d_in, const int* in_sizes, int n_in,
                              void* d_out, int out_size, void* d_ws, size_t ws_size,
                              hipStream_t stream) {
    const float* x    = (const float*)d_in[0];
    const int*   w32  = (const int*)d_in[1];   // int8 values stored as int32
    const float* bias = (const float*)d_in[2];
    const float* dqs  = (const float*)d_in[3];
    float* out = (float*)d_out;

    signed char* xq = (signed char*)d_ws;                                   // 33.55 MB
    float* qscale   = (float*)((char*)d_ws + (size_t)T_TOKENS * IN_F);      // 32 KB
    signed char* w8 = (signed char*)((char*)d_ws + (size_t)T_TOKENS * IN_F
                                     + (size_t)T_TOKENS * 4);               // 45 MB

    quant_kernel<<<T_TOKENS, 256, 0, stream>>>(x, xq, qscale);
    repack_kernel<<<2048, 256, 0, stream>>>(w32, w8, OUT_F * IN_F / 4);
    dim3 g((T_TOKENS / BM) * (OUT_F / BN));  // 32 * 43 = 1376
    gemm_kernel<<<g, 512, 0, stream>>>(xq, w8, qscale, bias, dqs, out);
}

// Round 3
// 535.456 us; speedup vs baseline: 1.1066x; 1.0414x over previous
//
#include <hip/hip_runtime.h>

#define T_TOKENS 8192
#define IN_F 4096
#define OUT_F 11008

#define BM 256
#define BN 256
#define BK 64
#define NT (IN_F / BK)  // 64 K-tiles

typedef __attribute__((ext_vector_type(4))) int v4i;
typedef __attribute__((ext_vector_type(16))) int v16i;

__device__ __forceinline__ void load_lds16(const signed char* g, const signed char* l) {
    __builtin_amdgcn_global_load_lds(
        (const __attribute__((address_space(1))) void*)g,
        (__attribute__((address_space(3))) void*)l, 16, 0, 0);
}

// ---------------- Pass 1: per-token activation quantization ----------------
__global__ __launch_bounds__(256) void quant_kernel(
        const float* __restrict__ x, signed char* __restrict__ xq,
        float* __restrict__ qscale) {
    const int row = blockIdx.x;
    const float4* xr = (const float4*)(x + (size_t)row * IN_F);
    float4 v[4];
    float am = 0.f;
#pragma unroll
    for (int i = 0; i < 4; ++i) {
        v[i] = xr[threadIdx.x + i * 256];
        am = fmaxf(am, fmaxf(fmaxf(fabsf(v[i].x), fabsf(v[i].y)),
                             fmaxf(fabsf(v[i].z), fabsf(v[i].w))));
    }
#pragma unroll
    for (int off = 32; off > 0; off >>= 1)
        am = fmaxf(am, __shfl_xor(am, off, 64));
    __shared__ float wmax[4];
    const int wid = threadIdx.x >> 6;
    if ((threadIdx.x & 63) == 0) wmax[wid] = am;
    __syncthreads();
    float amax = fmaxf(fmaxf(wmax[0], wmax[1]), fmaxf(wmax[2], wmax[3]));
    float qs = amax * (1.0f / 127.0f);
    if (qs < 1e-30f) qs = 1e-30f;
    const float inv = 1.0f / qs;
    if (threadIdx.x == 0) qscale[row] = qs;
    int* xqo = (int*)(xq + (size_t)row * IN_F);
#pragma unroll
    for (int i = 0; i < 4; ++i) {
        int q0 = (int)rintf(v[i].x * inv);
        int q1 = (int)rintf(v[i].y * inv);
        int q2 = (int)rintf(v[i].z * inv);
        int q3 = (int)rintf(v[i].w * inv);
        q0 = max(-128, min(127, q0));
        q1 = max(-128, min(127, q1));
        q2 = max(-128, min(127, q2));
        q3 = max(-128, min(127, q3));
        unsigned p = (unsigned)(q0 & 255) | ((unsigned)(q1 & 255) << 8) |
                     ((unsigned)(q2 & 255) << 16) | ((unsigned)(q3 & 255) << 24);
        xqo[threadIdx.x + i * 256] = (int)p;
    }
}

// ---------------- Pass 2: weight int32 -> int8 repack ----------------
__global__ __launch_bounds__(256) void repack_kernel(
        const int* __restrict__ w32, signed char* __restrict__ w8, int n4) {
    int idx = blockIdx.x * 256 + threadIdx.x;
    const int stride = gridDim.x * 256;
    for (int i = idx; i < n4; i += stride) {
        v4i w = ((const v4i*)w32)[i];
        unsigned p = (unsigned)(w[0] & 255) | ((unsigned)(w[1] & 255) << 8) |
                     ((unsigned)(w[2] & 255) << 16) | ((unsigned)(w[3] & 255) << 24);
        ((int*)w8)[i] = (int)p;
    }
}

// ---------------- Pass 3: int8 GEMM, 256x256, BK=64, 4-phase interleave ----
// 8 waves (2M x 4N), per-wave 128x64 via acc[4][2] of mfma_i32_32x32x32_i8.
// 3 LDS buffers (depth-2 prefetch), counted vmcnt(4) at tile boundary only.
// Each K-tile = 4 phases; phase p: {ds_read subtile | 1 gload chunk ->
// barrier -> lgkmcnt(0) -> setprio(1) 4 MFMA setprio(0) -> barrier}.
// Swizzle slot' = slot ^ ((row>>1)&3), both-sides (pre-swizzled global src,
// swizzled ds_read addr).
__global__ __launch_bounds__(512, 2) void gemm_kernel(
        const signed char* __restrict__ A, const signed char* __restrict__ B,
        const float* __restrict__ qscale, const float* __restrict__ bias,
        const float* __restrict__ dqs, float* __restrict__ out) {
    __shared__ __align__(16) signed char smem[3 * 32768];

    const int tid = threadIdx.x;
    const int wid = tid >> 6;   // 0..7
    const int lane = tid & 63;
    const int wm = wid >> 2;    // 0..1
    const int wn = wid & 3;     // 0..3
    const int l31 = lane & 31;
    const int hi = lane >> 5;

    // XCD map: XCD k owns m-tiles [4k,4k+4) (4MB A panel -> L2-resident),
    // sweeps n. Bijective for 1376 = 8*172 blocks.
    const int b = (int)blockIdx.x;
    const int xcd = b & 7;
    const int idx = b >> 3;                 // 0..171
    const int m0 = (xcd * 4 + (idx & 3)) * BM;
    const int n0 = (idx >> 2) * BN;         // 0..42

    // ---- staging precompute: 4 chunks of 8KB (A:0-1, B:2-3) ----
    const signed char* gSrc[4];
    int ldsOff[4];
#pragma unroll
    for (int c = 0; c < 4; ++c) {
        const int cc = c & 1;                       // chunk within A or B half
        const int L = cc * 8192 + tid * 16;         // linear offset in 16KB half
        const int row = L >> 6;                     // 0..255
        const int slot = (L >> 4) & 3;
        const int col = ((slot ^ ((row >> 1) & 3)) << 4);
        if (c < 2) {
            gSrc[c] = A + (size_t)(m0 + row) * IN_F + col;
            ldsOff[c] = cc * 8192 + wid * 1024;
        } else {
            gSrc[c] = B + (size_t)(n0 + row) * IN_F + col;
            ldsOff[c] = 16384 + cc * 8192 + wid * 1024;
        }
    }

    // ---- fragment LDS byte offsets (within buffer), swizzled ----
    int aOff[4][2], bOff[2][2];
#pragma unroll
    for (int im = 0; im < 4; ++im) {
        const int r = wm * 128 + im * 32 + l31;
#pragma unroll
        for (int ks = 0; ks < 2; ++ks) {
            const int slot = ks * 2 + hi;
            aOff[im][ks] = r * 64 + ((slot ^ ((r >> 1) & 3)) << 4);
        }
    }
#pragma unroll
    for (int in = 0; in < 2; ++in) {
        const int r = wn * 64 + in * 32 + l31;
#pragma unroll
        for (int ks = 0; ks < 2; ++ks) {
            const int slot = ks * 2 + hi;
            bOff[in][ks] = 16384 + r * 64 + ((slot ^ ((r >> 1) & 3)) << 4);
        }
    }

    v16i acc[4][2] = {};

    int bb0 = 0, bb1 = 32768, bb2 = 65536;
    // prologue: stage tiles 0 and 1
#pragma unroll
    for (int c = 0; c < 4; ++c) load_lds16(gSrc[c], smem + bb0 + ldsOff[c]);
#pragma unroll
    for (int c = 0; c < 4; ++c) load_lds16(gSrc[c] + BK, smem + bb1 + ldsOff[c]);
    asm volatile("s_waitcnt vmcnt(4)" ::: "memory");
    __builtin_amdgcn_sched_barrier(0);
    __builtin_amdgcn_s_barrier();

    for (int t = 0; t < NT; ++t) {
        const int koff2 = (t + 2) * BK;
        const bool stage = (t + 2 < NT);
        v4i a01[2][2], a23[2][2], b0[2], b1[2];

        // ---- phase 0: read a01 (4) + b0 (2); stage chunk 0; MFMA Q[0..1][0]
#pragma unroll
        for (int im = 0; im < 2; ++im)
#pragma unroll
            for (int ks = 0; ks < 2; ++ks)
                a01[im][ks] = *(const v4i*)(smem + bb0 + aOff[im][ks]);
#pragma unroll
        for (int ks = 0; ks < 2; ++ks)
            b0[ks] = *(const v4i*)(smem + bb0 + bOff[0][ks]);
        if (stage) load_lds16(gSrc[0] + koff2, smem + bb2 + ldsOff[0]);
        __builtin_amdgcn_sched_barrier(0);
        __builtin_amdgcn_s_barrier();
        asm volatile("s_waitcnt lgkmcnt(0)" ::: "memory");
        __builtin_amdgcn_sched_barrier(0);
        __builtin_amdgcn_s_setprio(1);
#pragma unroll
        for (int ks = 0; ks < 2; ++ks)
#pragma unroll
            for (int im = 0; im < 2; ++im)
                acc[im][0] = __builtin_amdgcn_mfma_i32_32x32x32_i8(
                    a01[im][ks], b0[ks], acc[im][0], 0, 0, 0);
        __builtin_amdgcn_s_setprio(0);
        __builtin_amdgcn_sched_barrier(0);
        __builtin_amdgcn_s_barrier();

        // ---- phase 1: read b1 (2); stage chunk 1; MFMA Q[0..1][1]
#pragma unroll
        for (int ks = 0; ks < 2; ++ks)
            b1[ks] = *(const v4i*)(smem + bb0 + bOff[1][ks]);
        if (stage) load_lds16(gSrc[1] + koff2, smem + bb2 + ldsOff[1]);
        __builtin_amdgcn_sched_barrier(0);
        __builtin_amdgcn_s_barrier();
        asm volatile("s_waitcnt lgkmcnt(0)" ::: "memory");
        __builtin_amdgcn_sched_barrier(0);
        __builtin_amdgcn_s_setprio(1);
#pragma unroll
        for (int ks = 0; ks < 2; ++ks)
#pragma unroll
            for (int im = 0; im < 2; ++im)
                acc[im][1] = __builtin_amdgcn_mfma_i32_32x32x32_i8(
                    a01[im][ks], b1[ks], acc[im][1], 0, 0, 0);
        __builtin_amdgcn_s_setprio(0);
        __builtin_amdgcn_sched_barrier(0);
        __builtin_amdgcn_s_barrier();

        // ---- phase 2: read a23 (4); stage chunk 2; MFMA Q[2..3][1]
#pragma unroll
        for (int im = 0; im < 2; ++im)
#pragma unroll
            for (int ks = 0; ks < 2; ++ks)
                a23[im][ks] = *(const v4i*)(smem + bb0 + aOff[2 + im][ks]);
        if (stage) load_lds16(gSrc[2] + koff2, smem + bb2 + ldsOff[2]);
        __builtin_amdgcn_sched_barrier(0);
        __builtin_amdgcn_s_barrier();
        asm volatile("s_waitcnt lgkmcnt(0)" ::: "memory");
        __builtin_amdgcn_sched_barrier(0);
        __builtin_amdgcn_s_setprio(1);
#pragma unroll
        for (int ks = 0; ks < 2; ++ks)
#pragma unroll
            for (int im = 0; im < 2; ++im)
                acc[2 + im][1] = __builtin_amdgcn_mfma_i32_32x32x32_i8(
                    a23[im][ks], b1[ks], acc[2 + im][1], 0, 0, 0);
        __builtin_amdgcn_s_setprio(0);
        __builtin_amdgcn_sched_barrier(0);
        __builtin_amdgcn_s_barrier();

        // ---- phase 3: no reads; stage chunk 3; MFMA Q[2..3][0]; tile sync
        if (stage) load_lds16(gSrc[3] + koff2, smem + bb2 + ldsOff[3]);
        __builtin_amdgcn_sched_barrier(0);
        __builtin_amdgcn_s_barrier();
        __builtin_amdgcn_s_setprio(1);
#pragma unroll
        for (int ks = 0; ks < 2; ++ks)
#pragma unroll
            for (int im = 0; im < 2; ++im)
                acc[2 + im][0] = __builtin_amdgcn_mfma_i32_32x32x32_i8(
                    a23[im][ks], b0[ks], acc[2 + im][0], 0, 0, 0);
        __builtin_amdgcn_s_setprio(0);
        __builtin_amdgcn_sched_barrier(0);
        // tile boundary: ensure buf for t+1 staged; keep t+2's 4 loads in flight
        if (t < NT - 2) {
            asm volatile("s_waitcnt vmcnt(4)" ::: "memory");
        } else {
            asm volatile("s_waitcnt vmcnt(0)" ::: "memory");
        }
        __builtin_amdgcn_sched_barrier(0);
        __builtin_amdgcn_s_barrier();

        const int tmp = bb0; bb0 = bb1; bb1 = bb2; bb2 = tmp;
    }

    // ---- epilogue: dequant + bias ----
    const float dq = dqs[0];
#pragma unroll
    for (int im = 0; im < 4; ++im) {
        float qsv[16];
#pragma unroll
        for (int r = 0; r < 16; ++r) {
            const int trow = wm * 128 + im * 32 + (r & 3) + 8 * (r >> 2) + 4 * hi;
            qsv[r] = dq * qscale[m0 + trow];
        }
#pragma unroll
        for (int in = 0; in < 2; ++in) {
            const int col = n0 + wn * 64 + in * 32 + l31;
            const float bv = bias[col];
#pragma unroll
            for (int r = 0; r < 16; ++r) {
                const int trow = wm * 128 + im * 32 + (r & 3) + 8 * (r >> 2) + 4 * hi;
                out[(size_t)(m0 + trow) * OUT_F + col] =
                    qsv[r] * (float)acc[im][in][r] + bv;
            }
        }
    }
}

extern "C" void kernel_launch(void* const* d_in, const int* in_sizes, int n_in,
                              void* d_out, int out_size, void* d_ws, size_t ws_size,
                              hipStream_t stream) {
    const float* x    = (const float*)d_in[0];
    const int*   w32  = (const int*)d_in[1];   // int8 values stored as int32
    const float* bias = (const float*)d_in[2];
    const float* dqs  = (const float*)d_in[3];
    float* out = (float*)d_out;

    signed char* xq = (signed char*)d_ws;                                   // 33.55 MB
    float* qscale   = (float*)((char*)d_ws + (size_t)T_TOKENS * IN_F);      // 32 KB
    signed char* w8 = (signed char*)((char*)d_ws + (size_t)T_TOKENS * IN_F
                                     + (size_t)T_TOKENS * 4);               // 45 MB

    quant_kernel<<<T_TOKENS, 256, 0, stream>>>(x, xq, qscale);
    repack_kernel<<<2048, 256, 0, stream>>>(w32, w8, OUT_F * IN_F / 4);
    dim3 g((T_TOKENS / BM) * (OUT_F / BN));  // 1376
    gemm_kernel<<<g, 512, 0, stream>>>(xq, w8, qscale, bias, dqs, out);
}

// Round 4
// 508.022 us; speedup vs baseline: 1.1664x; 1.0540x over previous
//
#include <hip/hip_runtime.h>

#define T_TOKENS 8192
#define IN_F 4096
#define OUT_F 11008

#define BM 256
#define BN 256
#define BK 64
#define NT (IN_F / BK)   // 64 K-tiles
#define NITER (NT / 2)   // 32 iterations x 2 K-tiles

typedef __attribute__((ext_vector_type(4))) int v4i;
typedef __attribute__((ext_vector_type(16))) int v16i;

__device__ __forceinline__ void load_lds16(const signed char* g, const signed char* l) {
    __builtin_amdgcn_global_load_lds(
        (const __attribute__((address_space(1))) void*)g,
        (__attribute__((address_space(3))) void*)l, 16, 0, 0);
}

// ------------- Pass 1: fused per-token quant + weight repack -------------
// Blocks [0,8192): quantize one token row. Blocks [8192,10240): repack stripes.
__global__ __launch_bounds__(256) void quant_repack_kernel(
        const float* __restrict__ x, signed char* __restrict__ xq,
        float* __restrict__ qscale, const int* __restrict__ w32,
        signed char* __restrict__ w8) {
    if (blockIdx.x < T_TOKENS) {
        const int row = blockIdx.x;
        const float4* xr = (const float4*)(x + (size_t)row * IN_F);
        float4 v[4];
        float am = 0.f;
#pragma unroll
        for (int i = 0; i < 4; ++i) {
            v[i] = xr[threadIdx.x + i * 256];
            am = fmaxf(am, fmaxf(fmaxf(fabsf(v[i].x), fabsf(v[i].y)),
                                 fmaxf(fabsf(v[i].z), fabsf(v[i].w))));
        }
#pragma unroll
        for (int off = 32; off > 0; off >>= 1)
            am = fmaxf(am, __shfl_xor(am, off, 64));
        __shared__ float wmax[4];
        const int wid = threadIdx.x >> 6;
        if ((threadIdx.x & 63) == 0) wmax[wid] = am;
        __syncthreads();
        float amax = fmaxf(fmaxf(wmax[0], wmax[1]), fmaxf(wmax[2], wmax[3]));
        float qs = amax * (1.0f / 127.0f);
        if (qs < 1e-30f) qs = 1e-30f;
        const float inv = 1.0f / qs;
        if (threadIdx.x == 0) qscale[row] = qs;
        int* xqo = (int*)(xq + (size_t)row * IN_F);
#pragma unroll
        for (int i = 0; i < 4; ++i) {
            int q0 = (int)rintf(v[i].x * inv);
            int q1 = (int)rintf(v[i].y * inv);
            int q2 = (int)rintf(v[i].z * inv);
            int q3 = (int)rintf(v[i].w * inv);
            q0 = max(-128, min(127, q0));
            q1 = max(-128, min(127, q1));
            q2 = max(-128, min(127, q2));
            q3 = max(-128, min(127, q3));
            unsigned p = (unsigned)(q0 & 255) | ((unsigned)(q1 & 255) << 8) |
                         ((unsigned)(q2 & 255) << 16) | ((unsigned)(q3 & 255) << 24);
            xqo[threadIdx.x + i * 256] = (int)p;
        }
    } else {
        const int n4 = OUT_F * IN_F / 4;
        int idx = (blockIdx.x - T_TOKENS) * 256 + threadIdx.x;
        const int stride = 2048 * 256;
        for (int i = idx; i < n4; i += stride) {
            v4i w = ((const v4i*)w32)[i];
            unsigned p = (unsigned)(w[0] & 255) | ((unsigned)(w[1] & 255) << 8) |
                         ((unsigned)(w[2] & 255) << 16) | ((unsigned)(w[3] & 255) << 24);
            ((int*)w8)[i] = (int)p;
        }
    }
}

// ------------- Pass 2: int8 GEMM, 256x256, 2 K-tiles/iter, 5-buffer ring -----
// 8 waves (2M x 4N), per-wave 128x64 via acc[4][2] of mfma_i32_32x32x32_i8.
// 5 LDS buffers x 32KB = 160KB; tile j resides in buf j%5. Iter i computes
// tiles 2i,2i+1; stages tile 2i+3 (phases 0-1) and 2i+4 (phases 2-3).
// 4 phases/iter, 8 MFMA each, ONE barrier per phase + one boundary barrier.
// Boundary s_waitcnt vmcnt(4) keeps tile 2i+4's loads in flight (no drain).
__global__ __launch_bounds__(512, 2) void gemm_kernel(
        const signed char* __restrict__ A, const signed char* __restrict__ B,
        const float* __restrict__ qscale, const float* __restrict__ bias,
        const float* __restrict__ dqs, float* __restrict__ out) {
    __shared__ __align__(16) signed char smem[5 * 32768];  // 160 KB

    const int tid = threadIdx.x;
    const int wid = tid >> 6;   // 0..7
    const int lane = tid & 63;
    const int wm = wid >> 2;    // 0..1
    const int wn = wid & 3;     // 0..3
    const int l31 = lane & 31;
    const int hi = lane >> 5;

    // XCD map: XCD k owns m-tiles [4k,4k+4) (4MB A panel -> L2-resident).
    const int b = (int)blockIdx.x;
    const int xcd = b & 7;
    const int idx = b >> 3;                 // 0..171
    const int m0 = (xcd * 4 + (idx & 3)) * BM;
    const int n0 = (idx >> 2) * BN;         // 0..42

    // ---- staging precompute: 4 chunks of 8KB per tile (A:0-1, B:2-3) ----
    const signed char* gSrc[4];
    int ldsOff[4];
#pragma unroll
    for (int c = 0; c < 4; ++c) {
        const int cc = c & 1;
        const int L = cc * 8192 + tid * 16;
        const int row = L >> 6;             // 0..255
        const int slot = (L >> 4) & 3;
        const int col = ((slot ^ ((row >> 1) & 3)) << 4);
        if (c < 2) {
            gSrc[c] = A + (size_t)(m0 + row) * IN_F + col;
            ldsOff[c] = cc * 8192 + wid * 1024;
        } else {
            gSrc[c] = B + (size_t)(n0 + row) * IN_F + col;
            ldsOff[c] = 16384 + cc * 8192 + wid * 1024;
        }
    }

    // ---- fragment LDS byte offsets (within buffer), swizzled ----
    int aOff[4][2], bOff[2][2];
#pragma unroll
    for (int im = 0; im < 4; ++im) {
        const int r = wm * 128 + im * 32 + l31;
#pragma unroll
        for (int ks = 0; ks < 2; ++ks) {
            const int slot = ks * 2 + hi;
            aOff[im][ks] = r * 64 + ((slot ^ ((r >> 1) & 3)) << 4);
        }
    }
#pragma unroll
    for (int in = 0; in < 2; ++in) {
        const int r = wn * 64 + in * 32 + l31;
#pragma unroll
        for (int ks = 0; ks < 2; ++ks) {
            const int slot = ks * 2 + hi;
            bOff[in][ks] = 16384 + r * 64 + ((slot ^ ((r >> 1) & 3)) << 4);
        }
    }

    v16i acc[4][2] = {};

    // ---- prologue: stage tiles 0,1,2 into bufs 0,1,2 (12 gloads) ----
#pragma unroll
    for (int tt = 0; tt < 3; ++tt)
#pragma unroll
        for (int c = 0; c < 4; ++c)
            load_lds16(gSrc[c] + tt * BK, smem + tt * 32768 + ldsOff[c]);
    asm volatile("s_waitcnt vmcnt(4)" ::: "memory");  // tiles 0,1 landed
    __builtin_amdgcn_sched_barrier(0);
    __builtin_amdgcn_s_barrier();

    int bx = 0;  // buf of tile 2i (tile j -> buf j%5)
    for (int i = 0; i < NITER; ++i) {
        const int t0 = 2 * i;
        const int by = (bx + 1 >= 5) ? bx - 4 : bx + 1;
        const int z3 = (bx + 3 >= 5) ? bx - 2 : bx + 3;  // tile t0+3
        const int z4 = (bx + 4 >= 5) ? bx - 1 : bx + 4;  // tile t0+4
        const signed char* s0 = smem + bx * 32768;
        const signed char* s1 = smem + by * 32768;
        const bool stA = (t0 + 3 < NT);
        const bool stB = (t0 + 4 < NT);
        const int k3 = (t0 + 3) * BK;
        const int k4 = (t0 + 4) * BK;

        v4i a[2][2], bf[2][2];

        // ---- phase 0: tile t0 top half. reads a01+b (8); stage t0+3 c0,c1
#pragma unroll
        for (int im = 0; im < 2; ++im)
#pragma unroll
            for (int ks = 0; ks < 2; ++ks)
                a[im][ks] = *(const v4i*)(s0 + aOff[im][ks]);
#pragma unroll
        for (int in = 0; in < 2; ++in)
#pragma unroll
            for (int ks = 0; ks < 2; ++ks)
                bf[in][ks] = *(const v4i*)(s0 + bOff[in][ks]);
        if (stA) {
            load_lds16(gSrc[0] + k3, smem + z3 * 32768 + ldsOff[0]);
            load_lds16(gSrc[1] + k3, smem + z3 * 32768 + ldsOff[1]);
        }
        __builtin_amdgcn_sched_barrier(0);
        __builtin_amdgcn_s_barrier();
        asm volatile("s_waitcnt lgkmcnt(0)" ::: "memory");
        __builtin_amdgcn_sched_barrier(0);
        __builtin_amdgcn_s_setprio(1);
#pragma unroll
        for (int ks = 0; ks < 2; ++ks)
#pragma unroll
            for (int im = 0; im < 2; ++im)
#pragma unroll
                for (int in = 0; in < 2; ++in)
                    acc[im][in] = __builtin_amdgcn_mfma_i32_32x32x32_i8(
                        a[im][ks], bf[in][ks], acc[im][in], 0, 0, 0);
        __builtin_amdgcn_s_setprio(0);

        // ---- phase 1: tile t0 bottom half. reads a23 (4); stage t0+3 c2,c3
#pragma unroll
        for (int im = 0; im < 2; ++im)
#pragma unroll
            for (int ks = 0; ks < 2; ++ks)
                a[im][ks] = *(const v4i*)(s0 + aOff[2 + im][ks]);
        if (stA) {
            load_lds16(gSrc[2] + k3, smem + z3 * 32768 + ldsOff[2]);
            load_lds16(gSrc[3] + k3, smem + z3 * 32768 + ldsOff[3]);
        }
        __builtin_amdgcn_sched_barrier(0);
        __builtin_amdgcn_s_barrier();
        asm volatile("s_waitcnt lgkmcnt(0)" ::: "memory");
        __builtin_amdgcn_sched_barrier(0);
        __builtin_amdgcn_s_setprio(1);
#pragma unroll
        for (int ks = 0; ks < 2; ++ks)
#pragma unroll
            for (int im = 0; im < 2; ++im)
#pragma unroll
                for (int in = 0; in < 2; ++in)
                    acc[2 + im][in] = __builtin_amdgcn_mfma_i32_32x32x32_i8(
                        a[im][ks], bf[in][ks], acc[2 + im][in], 0, 0, 0);
        __builtin_amdgcn_s_setprio(0);

        // ---- phase 2: tile t1 top half. reads a01'+b' (8); stage t0+4 c0,c1
#pragma unroll
        for (int im = 0; im < 2; ++im)
#pragma unroll
            for (int ks = 0; ks < 2; ++ks)
                a[im][ks] = *(const v4i*)(s1 + aOff[im][ks]);
#pragma unroll
        for (int in = 0; in < 2; ++in)
#pragma unroll
            for (int ks = 0; ks < 2; ++ks)
                bf[in][ks] = *(const v4i*)(s1 + bOff[in][ks]);
        if (stB) {
            load_lds16(gSrc[0] + k4, smem + z4 * 32768 + ldsOff[0]);
            load_lds16(gSrc[1] + k4, smem + z4 * 32768 + ldsOff[1]);
        }
        __builtin_amdgcn_sched_barrier(0);
        __builtin_amdgcn_s_barrier();
        asm volatile("s_waitcnt lgkmcnt(0)" ::: "memory");
        __builtin_amdgcn_sched_barrier(0);
        __builtin_amdgcn_s_setprio(1);
#pragma unroll
        for (int ks = 0; ks < 2; ++ks)
#pragma unroll
            for (int im = 0; im < 2; ++im)
#pragma unroll
                for (int in = 0; in < 2; ++in)
                    acc[im][in] = __builtin_amdgcn_mfma_i32_32x32x32_i8(
                        a[im][ks], bf[in][ks], acc[im][in], 0, 0, 0);
        __builtin_amdgcn_s_setprio(0);

        // ---- phase 3: tile t1 bottom half. reads a23' (4); stage t0+4 c2,c3
#pragma unroll
        for (int im = 0; im < 2; ++im)
#pragma unroll
            for (int ks = 0; ks < 2; ++ks)
                a[im][ks] = *(const v4i*)(s1 + aOff[2 + im][ks]);
        if (stB) {
            load_lds16(gSrc[2] + k4, smem + z4 * 32768 + ldsOff[2]);
            load_lds16(gSrc[3] + k4, smem + z4 * 32768 + ldsOff[3]);
        }
        __builtin_amdgcn_sched_barrier(0);
        __builtin_amdgcn_s_barrier();
        asm volatile("s_waitcnt lgkmcnt(0)" ::: "memory");
        __builtin_amdgcn_sched_barrier(0);
        __builtin_amdgcn_s_setprio(1);
#pragma unroll
        for (int ks = 0; ks < 2; ++ks)
#pragma unroll
            for (int im = 0; im < 2; ++im)
#pragma unroll
                for (int in = 0; in < 2; ++in)
                    acc[2 + im][in] = __builtin_amdgcn_mfma_i32_32x32x32_i8(
                        a[im][ks], bf[in][ks], acc[2 + im][in], 0, 0, 0);
        __builtin_amdgcn_s_setprio(0);

        // ---- iter boundary: tiles 2i+2,2i+3 must have landed; keep 2i+4 in flight
        __builtin_amdgcn_sched_barrier(0);
        if (stB) {
            asm volatile("s_waitcnt vmcnt(4)" ::: "memory");
        } else {
            asm volatile("s_waitcnt vmcnt(0)" ::: "memory");
        }
        __builtin_amdgcn_sched_barrier(0);
        __builtin_amdgcn_s_barrier();

        bx = (bx + 2 >= 5) ? bx - 3 : bx + 2;
    }

    // ---- epilogue: dequant + bias ----
    const float dq = dqs[0];
#pragma unroll
    for (int im = 0; im < 4; ++im) {
        float qsv[16];
#pragma unroll
        for (int r = 0; r < 16; ++r) {
            const int trow = wm * 128 + im * 32 + (r & 3) + 8 * (r >> 2) + 4 * hi;
            qsv[r] = dq * qscale[m0 + trow];
        }
#pragma unroll
        for (int in = 0; in < 2; ++in) {
            const int col = n0 + wn * 64 + in * 32 + l31;
            const float bv = bias[col];
#pragma unroll
            for (int r = 0; r < 16; ++r) {
                const int trow = wm * 128 + im * 32 + (r & 3) + 8 * (r >> 2) + 4 * hi;
                out[(size_t)(m0 + trow) * OUT_F + col] =
                    qsv[r] * (float)acc[im][in][r] + bv;
            }
        }
    }
}

extern "C" void kernel_launch(void* const* d_in, const int* in_sizes, int n_in,
                              void* d_out, int out_size, void* d_ws, size_t ws_size,
                              hipStream_t stream) {
    const float* x    = (const float*)d_in[0];
    const int*   w32  = (const int*)d_in[1];   // int8 values stored as int32
    const float* bias = (const float*)d_in[2];
    const float* dqs  = (const float*)d_in[3];
    float* out = (float*)d_out;

    signed char* xq = (signed char*)d_ws;                                   // 33.55 MB
    float* qscale   = (float*)((char*)d_ws + (size_t)T_TOKENS * IN_F);      // 32 KB
    signed char* w8 = (signed char*)((char*)d_ws + (size_t)T_TOKENS * IN_F
                                     + (size_t)T_TOKENS * 4);               // 45 MB

    quant_repack_kernel<<<T_TOKENS + 2048, 256, 0, stream>>>(x, xq, qscale, w32, w8);
    dim3 g((T_TOKENS / BM) * (OUT_F / BN));  // 1376
    gemm_kernel<<<g, 512, 0, stream>>>(xq, w8, qscale, bias, dqs, out);
}